// Round 5
// baseline (416.803 us; speedup 1.0000x reference)
//
#include <hip/hip_runtime.h>
#include <hip/hip_bf16.h>
#include <cstdint>
#include <cstddef>

#define Kn 32
#define Bn 512
#define Tn 2048
#define CH 128              // chunk length
#define NC (Tn / CH)        // 16 chunks per batch row
#define GP 8                // gold partials per batch row
#define NITEMS (Bn * NC)    // 8192 mm work items
#define GITEMS (Bn * GP)    // 4096 gold work items
#define PBLK 2048           // persistent blocks (256 thr): 8/CU -> full residency
#define START 30
#define STOP 31
#define LN2F 0.69314718055994530942f

typedef __attribute__((ext_vector_type(8))) short bf16x8;   // 8 bf16 (4 VGPRs)
typedef __attribute__((ext_vector_type(16))) float f32x16;  // MFMA 32x32 accum

union BF8 { bf16x8 v; unsigned u[4]; };

// pack two non-negative f32 -> bf16x2, round-toward-zero: single v_perm.
// (bias analysis: <= ~2^-8 rel/step * 2048 steps ~ -8 in log space, << threshold)
__device__ __forceinline__ unsigned pk2z(float lo, float hi) {
  return __builtin_amdgcn_perm(__float_as_uint(hi), __float_as_uint(lo),
                               0x07060302u);
}

__device__ __forceinline__ float bcast32(float v, int idx) {
  return __shfl(v, idx, 32);
}

// ---------------------------------------------------------------------------
// Persistent fused phase 1: waves steal work items off a global counter.
// Items [0, NITEMS): chunk products, c-major => biggest items first, empty
// chunks drain at the end.  Items [NITEMS, NITEMS+GITEMS): gold partials.
// P_new = diag(exp(feat_t))*exp(trans) * P_old via 2x mfma_f32_32x32x16_bf16.
// D layout: row=(r&3)+8*(r>>2)+4h, col=lane&31. A: A[m][k], m=lane&31, k=8h+j.
// B: B[k][n], n=lane&31, k=8h+j.
// ---------------------------------------------------------------------------
__global__ __launch_bounds__(256, 8) void crf_fused(
    const float* __restrict__ feats, const float* __restrict__ trans,
    const int* __restrict__ tags, const int* __restrict__ lens,
    float* __restrict__ pmats, float* __restrict__ poffs,
    float* __restrict__ gold_part, int* __restrict__ ctr) {
  const int lane = threadIdx.x & 63;
  const int m = lane & 31;
  const int h = lane >> 5;

  // E fragments with 2^-7 static renorm folded in; exp(-10000) == 0 exactly.
  float e1[8], e2[8];
  {
    const float* tr = trans + m * Kn + 8 * h;
#pragma unroll
    for (int j = 0; j < 8; ++j) {
      e1[j] = __expf(tr[j]) * 0.0078125f;
      e2[j] = __expf(tr[16 + j]) * 0.0078125f;
    }
  }
  // identity B-fragments (bf16 1.0 = 0x3F80), computed once per wave
  unsigned i1[4] = {0, 0, 0, 0}, i2[4] = {0, 0, 0, 0};
  {
    int j = m - 8 * h;
    if (0 <= j && j < 8) i1[j >> 1] = (j & 1) ? 0x3F800000u : 0x00003F80u;
    j = m - 16 - 8 * h;
    if (0 <= j && j < 8) i2[j >> 1] = (j & 1) ? 0x3F800000u : 0x00003F80u;
  }
  const f32x16 zf = {0.f, 0.f, 0.f, 0.f, 0.f, 0.f, 0.f, 0.f,
                     0.f, 0.f, 0.f, 0.f, 0.f, 0.f, 0.f, 0.f};

  for (;;) {
    int item;
    if (lane == 0) item = atomicAdd(ctr, 1);
    item = __shfl(item, 0);
    if (item >= NITEMS + GITEMS) break;

    if (item < NITEMS) {
      // ---------------- chunk product ----------------
      const int c = item >> 9;            // c-major: big chunks first
      const int b = item & (Bn - 1);
      const int len = lens[b];
      const int nsteps = min(max(len - c * CH, 0), CH);
      if (nsteps == 0) continue;          // never read by crf_apply

      unsigned b1u[4], b2u[4];
#pragma unroll
      for (int j = 0; j < 4; ++j) { b1u[j] = i1[j]; b2u[j] = i2[j]; }

      f32x16 acc;
      float off = 0.0f;
      const int t0 = c * CH;
      const float* fb = feats + ((size_t)b * Tn + t0) * Kn + m;
      const int lim = Tn - 1 - t0;        // clamp for prefetch

      float ring[8];
#pragma unroll
      for (int i = 0; i < 8; ++i) ring[i] = fb[(size_t)min(i, lim) * Kn];

      auto mmstep = [&](float f, bool rn) {
        const float w = __expf(f);
        BF8 A1, A2, B1, B2;
#pragma unroll
        for (int j = 0; j < 4; ++j) {
          A1.u[j] = pk2z(e1[2 * j] * w, e1[2 * j + 1] * w);
          A2.u[j] = pk2z(e2[2 * j] * w, e2[2 * j + 1] * w);
          B1.u[j] = b1u[j];
          B2.u[j] = b2u[j];
        }
        acc = __builtin_amdgcn_mfma_f32_32x32x16_bf16(A2.v, B2.v, zf, 0, 0, 0);
        acc = __builtin_amdgcn_mfma_f32_32x32x16_bf16(A1.v, B1.v, acc, 0, 0, 0);

        if (rn) {  // exact power-of-2 renorm
          float mx = acc[0];
#pragma unroll
          for (int r = 1; r < 16; ++r) mx = fmaxf(mx, acc[r]);
#pragma unroll
          for (int d = 1; d < 64; d <<= 1) mx = fmaxf(mx, __shfl_xor(mx, d));
          const int e = (int)((__float_as_uint(mx) >> 23) & 255u);
          const float sc = __uint_as_float((unsigned)(254 - e) << 23);
#pragma unroll
          for (int r = 0; r < 16; ++r) acc[r] *= sc;
          off += (float)(e - 127) * LN2F;
        }

        // D (f32) -> B fragments (bf16). Own rows packed, partner rows via
        // unconditional shfl_xor(32) (LDS pipe), h-dependent placement only.
        const unsigned qa = pk2z(acc[0], acc[1]);    // rows 4h+0,1
        const unsigned qb = pk2z(acc[2], acc[3]);    // rows 4h+2,3
        const unsigned qc = pk2z(acc[4], acc[5]);    // rows 8+4h+0,1
        const unsigned qd = pk2z(acc[6], acc[7]);    // rows 8+4h+2,3
        const unsigned qe = pk2z(acc[8], acc[9]);    // rows 16+4h+0,1
        const unsigned qf = pk2z(acc[10], acc[11]);  // rows 16+4h+2,3
        const unsigned qg = pk2z(acc[12], acc[13]);  // rows 24+4h+0,1
        const unsigned qh = pk2z(acc[14], acc[15]);  // rows 24+4h+2,3
        const unsigned ra = __shfl_xor(qa, 32);
        const unsigned rb = __shfl_xor(qb, 32);
        const unsigned rc = __shfl_xor(qc, 32);
        const unsigned rd = __shfl_xor(qd, 32);
        const unsigned re = __shfl_xor(qe, 32);
        const unsigned rf = __shfl_xor(qf, 32);
        const unsigned rg = __shfl_xor(qg, 32);
        const unsigned rh = __shfl_xor(qh, 32);
        // h=0: B1 rows (0,1),(2,3),(4,5),(6,7) = qa,qb,ra,rb
        // h=1: B1 rows (8,9),(10,11),(12,13),(14,15) = rc,rd,qc,qd
        b1u[0] = h ? rc : qa;
        b1u[1] = h ? rd : qb;
        b1u[2] = h ? qc : ra;
        b1u[3] = h ? qd : rb;
        b2u[0] = h ? rg : qe;
        b2u[1] = h ? rh : qf;
        b2u[2] = h ? qg : re;
        b2u[3] = h ? qh : rf;
      };

      int t = 0;
      const int nb = nsteps >> 3;
      for (int mb = 0; mb < nb; ++mb) {
#pragma unroll
        for (int i = 0; i < 8; ++i) {
          const float f = ring[i];
          ring[i] = fb[(size_t)min(t + i + 8, lim) * Kn];
          mmstep(f, ((t + i) & 31) == 31);
        }
        t += 8;
      }
      const int rem = nsteps & 7;
      for (int i = 0; i < rem; ++i) mmstep(ring[i], false);

      // store chunk product (f32, row-major) + log offset
      float* pm = pmats + (size_t)(b * NC + c) * (Kn * Kn);
#pragma unroll
      for (int r = 0; r < 16; ++r) {
        const int row = (r & 3) + 8 * (r >> 2) + 4 * h;
        pm[row * Kn + m] = acc[r];
      }
      if (lane == 0) poffs[b * NC + c] = off + 7.0f * LN2F * (float)nsteps;
    } else {
      // ---------------- gold partial sum (256-token span) ----------------
      const int g = item - NITEMS;
      const int b = g >> 3, p = g & 7;
      const int len = lens[b];
      const int t0 = p * 256;
      const int t1 = min(t0 + 256, len);
      const int* tg = tags + (size_t)b * Tn;
      const float* fbp = feats + (size_t)b * Tn * Kn;
      float acc = 0.f;
      for (int tt = t0 + lane; tt < t1; tt += 64) {
        const int tag = tg[tt];
        const int prev = tt ? tg[tt - 1] : START;
        acc += fbp[(size_t)tt * Kn + tag] + trans[tag * Kn + prev];
      }
      if (lane == 0 && ((len - 1) >> 8) == p)
        acc += trans[STOP * Kn + tg[len - 1]];
#pragma unroll
      for (int msk = 32; msk >= 1; msk >>= 1) acc += __shfl_xor(acc, msk);
      if (lane == 0) gold_part[b * GP + p] = acc;  // always written (0 if idle)
    }
  }
}

// ---------------------------------------------------------------------------
// Phase 2: apply <=16 chunk matrices serially per batch elem, fold gold
// partials and accumulate the mean into d_out (zeroed by memset each call).
// ---------------------------------------------------------------------------
__device__ __forceinline__ float renorm_s(float& s, float off) {
  int e = (int)((__float_as_uint(s) >> 23) & 255u);
  e = max(e, __shfl_xor(e, 1));
  e = max(e, __shfl_xor(e, 2));
  e = max(e, __shfl_xor(e, 4));
  e = max(e, __shfl_xor(e, 8));
  e = max(e, __shfl_xor(e, 16));
  s *= __uint_as_float((unsigned)(254 - e) << 23);
  return off + (float)(e - 127) * LN2F;
}

__global__ __launch_bounds__(64, 1) void crf_apply(
    const float* __restrict__ trans, const int* __restrict__ lens,
    const float* __restrict__ pmats, const float* __restrict__ poffs,
    const float* __restrict__ gold_part, float* __restrict__ out) {
  const int lane = threadIdx.x;
  const int b = blockIdx.x;
  const int n = lane & 31;
  const int hb = (lane >> 5) * 16;
  const int len = lens[b];
  const int nc = (len + CH - 1) / CH;
  float s = (n == START) ? 1.0f : 0.0f;
  float off = 0.0f;
  for (int c = 0; c < nc; ++c) {
    const float* pm = pmats + (size_t)(b * NC + c) * (Kn * Kn) + n * Kn + hb;
    const float4 p0 = *(const float4*)pm;
    const float4 p1 = *(const float4*)(pm + 4);
    const float4 p2 = *(const float4*)(pm + 8);
    const float4 p3 = *(const float4*)(pm + 12);
    float a0 = 0.f, a1 = 0.f, a2 = 0.f, a3 = 0.f;
    a0 = fmaf(bcast32(s, hb + 0), p0.x, a0);
    a0 = fmaf(bcast32(s, hb + 1), p0.y, a0);
    a0 = fmaf(bcast32(s, hb + 2), p0.z, a0);
    a0 = fmaf(bcast32(s, hb + 3), p0.w, a0);
    a1 = fmaf(bcast32(s, hb + 4), p1.x, a1);
    a1 = fmaf(bcast32(s, hb + 5), p1.y, a1);
    a1 = fmaf(bcast32(s, hb + 6), p1.z, a1);
    a1 = fmaf(bcast32(s, hb + 7), p1.w, a1);
    a2 = fmaf(bcast32(s, hb + 8), p2.x, a2);
    a2 = fmaf(bcast32(s, hb + 9), p2.y, a2);
    a2 = fmaf(bcast32(s, hb + 10), p2.z, a2);
    a2 = fmaf(bcast32(s, hb + 11), p2.w, a2);
    a3 = fmaf(bcast32(s, hb + 12), p3.x, a3);
    a3 = fmaf(bcast32(s, hb + 13), p3.y, a3);
    a3 = fmaf(bcast32(s, hb + 14), p3.z, a3);
    a3 = fmaf(bcast32(s, hb + 15), p3.w, a3);
    float p = (a0 + a1) + (a2 + a3);
    p += __shfl_xor(p, 32);
    s = p;
    off = renorm_s(s, off);
    off += poffs[b * NC + c];
  }
  const float es = __expf(trans[STOP * Kn + n]);
  float q = s * es;
#pragma unroll
  for (int d = 1; d < 32; d <<= 1) q += __shfl_xor(q, d);
  if (lane == 0) {
    const float fs = __logf(q) + off;
    float gs = 0.f;
#pragma unroll
    for (int p = 0; p < GP; ++p) gs += gold_part[b * GP + p];
    atomicAdd(out, (fs - gs) * (1.0f / (float)Bn));
  }
}

extern "C" void kernel_launch(void* const* d_in, const int* in_sizes, int n_in,
                              void* d_out, int out_size, void* d_ws, size_t ws_size,
                              hipStream_t stream) {
  const float* feats = (const float*)d_in[0];
  const float* trans = (const float*)d_in[1];
  const int* tags = (const int*)d_in[2];
  const int* lens = (const int*)d_in[3];

  // ws layout (floats): [4 ctr][Bn*GP gold][Bn*NC poffs][Bn*NC*1024 pmats]
  int* ctr = (int*)d_ws;
  float* gold_part = (float*)d_ws + 4;
  float* poffs = gold_part + (size_t)Bn * GP;
  float* pmats = poffs + (size_t)Bn * NC;   // 16B-aligned (offset 49168 B)

  hipMemsetAsync(ctr, 0, 16, stream);
  hipMemsetAsync(d_out, 0, (size_t)out_size * sizeof(float), stream);
  crf_fused<<<PBLK, 256, 0, stream>>>(feats, trans, tags, lens, pmats, poffs,
                                      gold_part, ctr);
  crf_apply<<<Bn, 64, 0, stream>>>(trans, lens, pmats, poffs, gold_part,
                                   (float*)d_out);
}

// Round 6
// 415.440 us; speedup vs baseline: 1.0033x; 1.0033x over previous
//
#include <hip/hip_runtime.h>
#include <hip/hip_bf16.h>
#include <cstdint>
#include <cstddef>

#define Kn 32
#define Bn 512
#define Tn 2048
#define CH 128              // chunk length
#define NC (Tn / CH)        // 16 chunks per batch row
#define GP 8                // gold partials per batch row
#define NITEMS (Bn * NC)    // 8192 mm work items
#define GITEMS (Bn * GP)    // 4096 gold work items
#define PBLK 2048           // persistent blocks; extras drain the counter and exit
#define START 30
#define STOP 31
#define LN2F 0.69314718055994530942f

typedef __attribute__((ext_vector_type(8))) short bf16x8;   // 8 bf16 (4 VGPRs)
typedef __attribute__((ext_vector_type(16))) float f32x16;  // MFMA 32x32 accum
typedef __attribute__((ext_vector_type(2))) float f32x2;    // packed f32 pair

union BF8 { bf16x8 v; unsigned u[4]; };

// pack two non-negative f32 -> bf16x2, round-toward-zero: single v_perm.
// (truncation bias ~2^-8/step over <=2048 steps shifts scores by ~-8 max,
//  far under the 90.88 absmax threshold; R5 measured absmax 0.0)
__device__ __forceinline__ unsigned pk2z(float lo, float hi) {
  return __builtin_amdgcn_perm(__float_as_uint(hi), __float_as_uint(lo),
                               0x07060302u);
}

__device__ __forceinline__ float bcast32(float v, int idx) {
  return __shfl(v, idx, 32);
}

// ---------------------------------------------------------------------------
// Persistent fused phase 1: waves steal work items off a global counter.
// Items [0, NITEMS): chunk products (c-major). Items [NITEMS, +GITEMS): gold
// partial sums (small items -> tapering tail for load balance).
// P_new = diag(exp(feat_t))*exp(trans) * P_old via 2x mfma_f32_32x32x16_bf16.
// D layout: row=(r&3)+8*(r>>2)+4h, col=lane&31. A: A[m][k], m=lane&31, k=8h+j.
// B: B[k][n], n=lane&31, k=8h+j.
// NOTE __launch_bounds__(256,4): reg budget 128/wave. (256,8) in R5 capped it
// at 64 and spilled acc/ring to scratch (+44MB WRITE, VALUBusy 59->18%).
// ---------------------------------------------------------------------------
__global__ __launch_bounds__(256, 4) void crf_fused(
    const float* __restrict__ feats, const float* __restrict__ trans,
    const int* __restrict__ tags, const int* __restrict__ lens,
    float* __restrict__ pmats, float* __restrict__ poffs,
    float* __restrict__ gold_part, int* __restrict__ ctr) {
  const int lane = threadIdx.x & 63;
  const int m = lane & 31;
  const int h = lane >> 5;

  // E fragments (f32 pairs) with 2^-7 static renorm folded in; exp(-1e4)==0.
  f32x2 e1[4], e2[4];
  {
    const float* tr = trans + m * Kn + 8 * h;
#pragma unroll
    for (int j = 0; j < 4; ++j) {
      e1[j] = (f32x2){__expf(tr[2 * j]) * 0.0078125f,
                      __expf(tr[2 * j + 1]) * 0.0078125f};
      e2[j] = (f32x2){__expf(tr[16 + 2 * j]) * 0.0078125f,
                      __expf(tr[16 + 2 * j + 1]) * 0.0078125f};
    }
  }
  // identity B-fragments (bf16 1.0 = 0x3F80), computed once per wave
  unsigned i1[4] = {0, 0, 0, 0}, i2[4] = {0, 0, 0, 0};
  {
    int j = m - 8 * h;
    if (0 <= j && j < 8) i1[j >> 1] = (j & 1) ? 0x3F800000u : 0x00003F80u;
    j = m - 16 - 8 * h;
    if (0 <= j && j < 8) i2[j >> 1] = (j & 1) ? 0x3F800000u : 0x00003F80u;
  }
  const f32x16 zf = {0.f, 0.f, 0.f, 0.f, 0.f, 0.f, 0.f, 0.f,
                     0.f, 0.f, 0.f, 0.f, 0.f, 0.f, 0.f, 0.f};

  for (;;) {
    int item;
    if (lane == 0) item = atomicAdd(ctr, 1);
    item = __shfl(item, 0);
    if (item >= NITEMS + GITEMS) break;

    if (item < NITEMS) {
      // ---------------- chunk product ----------------
      const int c = item >> 9;
      const int b = item & (Bn - 1);
      const int len = lens[b];
      const int nsteps = min(max(len - c * CH, 0), CH);
      if (nsteps == 0) continue;          // never read by crf_apply

      unsigned b1u[4], b2u[4];
#pragma unroll
      for (int j = 0; j < 4; ++j) { b1u[j] = i1[j]; b2u[j] = i2[j]; }

      f32x16 acc;
      float off = 0.0f;
      const int t0 = c * CH;
      const float* fb = feats + ((size_t)b * Tn + t0) * Kn + m;
      const int lim = Tn - 1 - t0;        // clamp for prefetch

      float ring[8];
#pragma unroll
      for (int i = 0; i < 8; ++i) ring[i] = fb[(size_t)min(i, lim) * Kn];

      auto mmstep = [&](float f, bool rn) {
        const float w = __expf(f);
        const f32x2 w2 = {w, w};
        BF8 A1, A2, B1, B2;
#pragma unroll
        for (int j = 0; j < 4; ++j) {
          const f32x2 p1 = e1[j] * w2;    // candidates for v_pk_mul_f32
          const f32x2 p2 = e2[j] * w2;
          A1.u[j] = pk2z(p1.x, p1.y);
          A2.u[j] = pk2z(p2.x, p2.y);
          B1.u[j] = b1u[j];
          B2.u[j] = b2u[j];
        }
        acc = __builtin_amdgcn_mfma_f32_32x32x16_bf16(A2.v, B2.v, zf, 0, 0, 0);
        acc = __builtin_amdgcn_mfma_f32_32x32x16_bf16(A1.v, B1.v, acc, 0, 0, 0);

        if (rn) {  // exact power-of-2 renorm
          float mx = acc[0];
#pragma unroll
          for (int r = 1; r < 16; ++r) mx = fmaxf(mx, acc[r]);
#pragma unroll
          for (int d = 1; d < 64; d <<= 1) mx = fmaxf(mx, __shfl_xor(mx, d));
          const int e = (int)((__float_as_uint(mx) >> 23) & 255u);
          const float sc = __uint_as_float((unsigned)(254 - e) << 23);
#pragma unroll
          for (int r = 0; r < 16; ++r) acc[r] *= sc;
          off += (float)(e - 127) * LN2F;
        }

        // D (f32) -> B fragments (bf16). Own rows packed, partner rows via
        // unconditional shfl_xor(32), h-dependent placement selects.
        const unsigned qa = pk2z(acc[0], acc[1]);
        const unsigned qb = pk2z(acc[2], acc[3]);
        const unsigned qc = pk2z(acc[4], acc[5]);
        const unsigned qd = pk2z(acc[6], acc[7]);
        const unsigned qe = pk2z(acc[8], acc[9]);
        const unsigned qf = pk2z(acc[10], acc[11]);
        const unsigned qg = pk2z(acc[12], acc[13]);
        const unsigned qh = pk2z(acc[14], acc[15]);
        const unsigned ra = __shfl_xor(qa, 32);
        const unsigned rb = __shfl_xor(qb, 32);
        const unsigned rc = __shfl_xor(qc, 32);
        const unsigned rd = __shfl_xor(qd, 32);
        const unsigned re = __shfl_xor(qe, 32);
        const unsigned rf = __shfl_xor(qf, 32);
        const unsigned rg = __shfl_xor(qg, 32);
        const unsigned rh = __shfl_xor(qh, 32);
        b1u[0] = h ? rc : qa;
        b1u[1] = h ? rd : qb;
        b1u[2] = h ? qc : ra;
        b1u[3] = h ? qd : rb;
        b2u[0] = h ? rg : qe;
        b2u[1] = h ? rh : qf;
        b2u[2] = h ? qg : re;
        b2u[3] = h ? qh : rf;
      };

      int t = 0;
      const int nb = nsteps >> 3;
      for (int mb = 0; mb < nb; ++mb) {
#pragma unroll
        for (int i = 0; i < 8; ++i) {
          const float f = ring[i];
          ring[i] = fb[(size_t)min(t + i + 8, lim) * Kn];
          mmstep(f, ((t + i) & 31) == 31);
        }
        t += 8;
      }
      const int rem = nsteps & 7;
      for (int i = 0; i < rem; ++i) mmstep(ring[i], false);

      // store chunk product (f32, row-major) + log offset
      float* pm = pmats + (size_t)(b * NC + c) * (Kn * Kn);
#pragma unroll
      for (int r = 0; r < 16; ++r) {
        const int row = (r & 3) + 8 * (r >> 2) + 4 * h;
        pm[row * Kn + m] = acc[r];
      }
      if (lane == 0) poffs[b * NC + c] = off + 7.0f * LN2F * (float)nsteps;
    } else {
      // ---------------- gold partial sum (256-token span) ----------------
      const int g = item - NITEMS;
      const int b = g >> 3, p = g & 7;
      const int len = lens[b];
      const int t0 = p * 256;
      const int t1 = min(t0 + 256, len);
      const int* tg = tags + (size_t)b * Tn;
      const float* fbp = feats + (size_t)b * Tn * Kn;
      float acc = 0.f;
      for (int tt = t0 + lane; tt < t1; tt += 64) {
        const int tag = tg[tt];
        const int prev = tt ? tg[tt - 1] : START;
        acc += fbp[(size_t)tt * Kn + tag] + trans[tag * Kn + prev];
      }
      if (lane == 0 && ((len - 1) >> 8) == p)
        acc += trans[STOP * Kn + tg[len - 1]];
#pragma unroll
      for (int msk = 32; msk >= 1; msk >>= 1) acc += __shfl_xor(acc, msk);
      if (lane == 0) gold_part[b * GP + p] = acc;  // always written (0 if idle)
    }
  }
}

// ---------------------------------------------------------------------------
// Phase 2: apply <=16 chunk matrices serially per batch elem, fold gold
// partials and accumulate the mean into d_out (zeroed by memset each call).
// ---------------------------------------------------------------------------
__device__ __forceinline__ float renorm_s(float& s, float off) {
  int e = (int)((__float_as_uint(s) >> 23) & 255u);
  e = max(e, __shfl_xor(e, 1));
  e = max(e, __shfl_xor(e, 2));
  e = max(e, __shfl_xor(e, 4));
  e = max(e, __shfl_xor(e, 8));
  e = max(e, __shfl_xor(e, 16));
  s *= __uint_as_float((unsigned)(254 - e) << 23);
  return off + (float)(e - 127) * LN2F;
}

__global__ __launch_bounds__(64, 1) void crf_apply(
    const float* __restrict__ trans, const int* __restrict__ lens,
    const float* __restrict__ pmats, const float* __restrict__ poffs,
    const float* __restrict__ gold_part, float* __restrict__ out) {
  const int lane = threadIdx.x;
  const int b = blockIdx.x;
  const int n = lane & 31;
  const int hb = (lane >> 5) * 16;
  const int len = lens[b];
  const int nc = (len + CH - 1) / CH;
  float s = (n == START) ? 1.0f : 0.0f;
  float off = 0.0f;
  for (int c = 0; c < nc; ++c) {
    const float* pm = pmats + (size_t)(b * NC + c) * (Kn * Kn) + n * Kn + hb;
    const float4 p0 = *(const float4*)pm;
    const float4 p1 = *(const float4*)(pm + 4);
    const float4 p2 = *(const float4*)(pm + 8);
    const float4 p3 = *(const float4*)(pm + 12);
    float a0 = 0.f, a1 = 0.f, a2 = 0.f, a3 = 0.f;
    a0 = fmaf(bcast32(s, hb + 0), p0.x, a0);
    a0 = fmaf(bcast32(s, hb + 1), p0.y, a0);
    a0 = fmaf(bcast32(s, hb + 2), p0.z, a0);
    a0 = fmaf(bcast32(s, hb + 3), p0.w, a0);
    a1 = fmaf(bcast32(s, hb + 4), p1.x, a1);
    a1 = fmaf(bcast32(s, hb + 5), p1.y, a1);
    a1 = fmaf(bcast32(s, hb + 6), p1.z, a1);
    a1 = fmaf(bcast32(s, hb + 7), p1.w, a1);
    a2 = fmaf(bcast32(s, hb + 8), p2.x, a2);
    a2 = fmaf(bcast32(s, hb + 9), p2.y, a2);
    a2 = fmaf(bcast32(s, hb + 10), p2.z, a2);
    a2 = fmaf(bcast32(s, hb + 11), p2.w, a2);
    a3 = fmaf(bcast32(s, hb + 12), p3.x, a3);
    a3 = fmaf(bcast32(s, hb + 13), p3.y, a3);
    a3 = fmaf(bcast32(s, hb + 14), p3.z, a3);
    a3 = fmaf(bcast32(s, hb + 15), p3.w, a3);
    float p = (a0 + a1) + (a2 + a3);
    p += __shfl_xor(p, 32);
    s = p;
    off = renorm_s(s, off);
    off += poffs[b * NC + c];
  }
  const float es = __expf(trans[STOP * Kn + n]);
  float q = s * es;
#pragma unroll
  for (int d = 1; d < 32; d <<= 1) q += __shfl_xor(q, d);
  if (lane == 0) {
    const float fs = __logf(q) + off;
    float gs = 0.f;
#pragma unroll
    for (int p = 0; p < GP; ++p) gs += gold_part[b * GP + p];
    atomicAdd(out, (fs - gs) * (1.0f / (float)Bn));
  }
}

extern "C" void kernel_launch(void* const* d_in, const int* in_sizes, int n_in,
                              void* d_out, int out_size, void* d_ws, size_t ws_size,
                              hipStream_t stream) {
  const float* feats = (const float*)d_in[0];
  const float* trans = (const float*)d_in[1];
  const int* tags = (const int*)d_in[2];
  const int* lens = (const int*)d_in[3];

  // ws layout (floats): [4 ctr][Bn*GP gold][Bn*NC poffs][Bn*NC*1024 pmats]
  int* ctr = (int*)d_ws;
  float* gold_part = (float*)d_ws + 4;
  float* poffs = gold_part + (size_t)Bn * GP;
  float* pmats = poffs + (size_t)Bn * NC;   // 16B-aligned

  hipMemsetAsync(ctr, 0, 16, stream);
  hipMemsetAsync(d_out, 0, (size_t)out_size * sizeof(float), stream);
  crf_fused<<<PBLK, 256, 0, stream>>>(feats, trans, tags, lens, pmats, poffs,
                                      gold_part, ctr);
  crf_apply<<<Bn, 64, 0, stream>>>(trans, lens, pmats, poffs, gold_part,
                                   (float*)d_out);
}

// Round 7
// 286.592 us; speedup vs baseline: 1.4543x; 1.4496x over previous
//
#include <hip/hip_runtime.h>
#include <hip/hip_bf16.h>
#include <cstdint>
#include <cstddef>

#define Kn 32
#define Bn 512
#define Tn 2048
#define CH 128              // chunk length
#define NC (Tn / CH)        // 16 chunks per batch row
#define GP 4                // gold partials per batch row (1 per wave)
#define MMB (Bn * 2)        // 1024 mm blocks: (b, g), 4 waves each
#define GB  Bn              // 512 gold blocks, 4 waves each
#define START 30
#define STOP 31
#define LN2F 0.69314718055994530942f

typedef __attribute__((ext_vector_type(8))) short bf16x8;   // 8 bf16 (4 VGPRs)
typedef __attribute__((ext_vector_type(16))) float f32x16;  // MFMA 32x32 accum
typedef __attribute__((ext_vector_type(2))) float f32x2;    // packed f32 pair

union BF8 { bf16x8 v; unsigned u[4]; };

// pack two non-negative f32 -> bf16x2, round-toward-zero: single v_perm.
// (R5/R6 measured absmax 0.0 with this path)
__device__ __forceinline__ unsigned pk2z(float lo, float hi) {
  return __builtin_amdgcn_perm(__float_as_uint(hi), __float_as_uint(lo),
                               0x07060302u);
}

__device__ __forceinline__ float bcast32(float v, int idx) {
  return __shfl(v, idx, 32);
}

// ---------------------------------------------------------------------------
// Fused phase 1, STATIC balanced schedule (no work-stealing — R5/R6 showed the
// persistent counter loop doubles stall exposure vs static dispatch).
// mm blocks: b = blockIdx>>1, wave widx = (blockIdx&1)*4 + wid handles chunks
// c = widx and widx+8 sequentially. A row with ceil(len/128) real chunks
// spreads them evenly over its 8 waves -> balanced block lifetimes.
// P_new = diag(exp(feat_t))*exp(trans) * P_old via 2x mfma_f32_32x32x16_bf16.
// D layout: row=(r&3)+8*(r>>2)+4h, col=lane&31. A: A[m][k], m=lane&31, k=8h+j.
// B: B[k][n], n=lane&31, k=8h+j.
// NOTE __launch_bounds__(256,4): reg budget 128/wave. (256,8) capped at 64 and
// spilled acc/ring to scratch (R5: +44MB WRITE, VALUBusy collapse).
// ---------------------------------------------------------------------------
__global__ __launch_bounds__(256, 4) void crf_fused(
    const float* __restrict__ feats, const float* __restrict__ trans,
    const int* __restrict__ tags, const int* __restrict__ lens,
    float* __restrict__ pmats, float* __restrict__ poffs,
    float* __restrict__ gold_part) {
  const int wid = threadIdx.x >> 6;
  const int lane = threadIdx.x & 63;

  if (blockIdx.x < MMB) {
    const int b = blockIdx.x >> 1;
    const int widx = (blockIdx.x & 1) * 4 + wid;    // 0..7
    const int len = lens[b];
    const int m = lane & 31;
    const int h = lane >> 5;

    // E fragments (f32 pairs) with 2^-7 static renorm folded in; exp(-1e4)==0.
    f32x2 e1[4], e2[4];
    {
      const float* tr = trans + m * Kn + 8 * h;
#pragma unroll
      for (int j = 0; j < 4; ++j) {
        e1[j] = (f32x2){__expf(tr[2 * j]) * 0.0078125f,
                        __expf(tr[2 * j + 1]) * 0.0078125f};
        e2[j] = (f32x2){__expf(tr[16 + 2 * j]) * 0.0078125f,
                        __expf(tr[16 + 2 * j + 1]) * 0.0078125f};
      }
    }
    // identity B-fragments (bf16 1.0 = 0x3F80)
    unsigned i1[4] = {0, 0, 0, 0}, i2[4] = {0, 0, 0, 0};
    {
      int j = m - 8 * h;
      if (0 <= j && j < 8) i1[j >> 1] = (j & 1) ? 0x3F800000u : 0x00003F80u;
      j = m - 16 - 8 * h;
      if (0 <= j && j < 8) i2[j >> 1] = (j & 1) ? 0x3F800000u : 0x00003F80u;
    }
    const f32x16 zf = {0.f, 0.f, 0.f, 0.f, 0.f, 0.f, 0.f, 0.f,
                       0.f, 0.f, 0.f, 0.f, 0.f, 0.f, 0.f, 0.f};

    for (int cc = 0; cc < 2; ++cc) {
      const int c = widx + cc * 8;
      const int nsteps = min(max(len - c * CH, 0), CH);
      if (nsteps == 0) break;             // c+8 would be empty too

      unsigned b1u[4], b2u[4];
#pragma unroll
      for (int j = 0; j < 4; ++j) { b1u[j] = i1[j]; b2u[j] = i2[j]; }

      f32x16 acc;
      float off = 0.0f;
      const int t0 = c * CH;
      const float* fb = feats + ((size_t)b * Tn + t0) * Kn + m;
      const int lim = Tn - 1 - t0;        // clamp for prefetch

      float ring[8];
#pragma unroll
      for (int i = 0; i < 8; ++i) ring[i] = fb[(size_t)min(i, lim) * Kn];

      auto mmstep = [&](float f, bool rn) {
        const float w = __expf(f);
        const f32x2 w2 = {w, w};
        BF8 A1, A2, B1, B2;
#pragma unroll
        for (int j = 0; j < 4; ++j) {
          const f32x2 p1 = e1[j] * w2;
          const f32x2 p2 = e2[j] * w2;
          A1.u[j] = pk2z(p1.x, p1.y);
          A2.u[j] = pk2z(p2.x, p2.y);
          B1.u[j] = b1u[j];
          B2.u[j] = b2u[j];
        }
        acc = __builtin_amdgcn_mfma_f32_32x32x16_bf16(A2.v, B2.v, zf, 0, 0, 0);
        acc = __builtin_amdgcn_mfma_f32_32x32x16_bf16(A1.v, B1.v, acc, 0, 0, 0);

        if (rn) {  // exact power-of-2 renorm
          float mx = acc[0];
#pragma unroll
          for (int r = 1; r < 16; ++r) mx = fmaxf(mx, acc[r]);
#pragma unroll
          for (int d = 1; d < 64; d <<= 1) mx = fmaxf(mx, __shfl_xor(mx, d));
          const int e = (int)((__float_as_uint(mx) >> 23) & 255u);
          const float sc = __uint_as_float((unsigned)(254 - e) << 23);
#pragma unroll
          for (int r = 0; r < 16; ++r) acc[r] *= sc;
          off += (float)(e - 127) * LN2F;
        }

        // D (f32) -> B fragments (bf16): own rows packed, partner rows via
        // unconditional shfl_xor(32), h-dependent placement selects.
        const unsigned qa = pk2z(acc[0], acc[1]);
        const unsigned qb = pk2z(acc[2], acc[3]);
        const unsigned qc = pk2z(acc[4], acc[5]);
        const unsigned qd = pk2z(acc[6], acc[7]);
        const unsigned qe = pk2z(acc[8], acc[9]);
        const unsigned qf = pk2z(acc[10], acc[11]);
        const unsigned qg = pk2z(acc[12], acc[13]);
        const unsigned qh = pk2z(acc[14], acc[15]);
        const unsigned ra = __shfl_xor(qa, 32);
        const unsigned rb = __shfl_xor(qb, 32);
        const unsigned rc = __shfl_xor(qc, 32);
        const unsigned rd = __shfl_xor(qd, 32);
        const unsigned re = __shfl_xor(qe, 32);
        const unsigned rf = __shfl_xor(qf, 32);
        const unsigned rg = __shfl_xor(qg, 32);
        const unsigned rh = __shfl_xor(qh, 32);
        b1u[0] = h ? rc : qa;
        b1u[1] = h ? rd : qb;
        b1u[2] = h ? qc : ra;
        b1u[3] = h ? qd : rb;
        b2u[0] = h ? rg : qe;
        b2u[1] = h ? rh : qf;
        b2u[2] = h ? qg : re;
        b2u[3] = h ? qh : rf;
      };

      int t = 0;
      const int nb = nsteps >> 3;
      for (int mb = 0; mb < nb; ++mb) {
#pragma unroll
        for (int i = 0; i < 8; ++i) {
          const float f = ring[i];
          ring[i] = fb[(size_t)min(t + i + 8, lim) * Kn];
          mmstep(f, ((t + i) & 31) == 31);
        }
        t += 8;
      }
      const int rem = nsteps & 7;
      for (int i = 0; i < rem; ++i) mmstep(ring[i], false);

      // store chunk product (f32, row-major) + log offset
      float* pm = pmats + (size_t)(b * NC + c) * (Kn * Kn);
#pragma unroll
      for (int r = 0; r < 16; ++r) {
        const int row = (r & 3) + 8 * (r >> 2) + 4 * h;
        pm[row * Kn + m] = acc[r];
      }
      if (lane == 0) poffs[b * NC + c] = off + 7.0f * LN2F * (float)nsteps;
    }
  } else {
    // ------- gold partial sums: 4 waves/b, wave wid takes tt = 64*wid+lane
    //         + 256*k (interleaved stride -> balanced regardless of len) -----
    const int b = blockIdx.x - MMB;
    const int len = lens[b];
    const int* tg = tags + (size_t)b * Tn;
    const float* fbp = feats + (size_t)b * Tn * Kn;
    float acc = 0.f;
    for (int tt = 64 * wid + lane; tt < len; tt += 256) {
      const int tag = tg[tt];
      const int prev = tt ? tg[tt - 1] : START;
      acc += fbp[(size_t)tt * Kn + tag] + trans[tag * Kn + prev];
      if (tt == len - 1) acc += trans[STOP * Kn + tag];
    }
#pragma unroll
    for (int msk = 32; msk >= 1; msk >>= 1) acc += __shfl_xor(acc, msk);
    if (lane == 0) gold_part[b * GP + wid] = acc;   // always written
  }
}

// ---------------------------------------------------------------------------
// Phase 2: apply <=16 chunk matrices serially per batch elem, fold gold
// partials and accumulate the mean into d_out (zeroed by memset each call).
// ---------------------------------------------------------------------------
__device__ __forceinline__ float renorm_s(float& s, float off) {
  int e = (int)((__float_as_uint(s) >> 23) & 255u);
  e = max(e, __shfl_xor(e, 1));
  e = max(e, __shfl_xor(e, 2));
  e = max(e, __shfl_xor(e, 4));
  e = max(e, __shfl_xor(e, 8));
  e = max(e, __shfl_xor(e, 16));
  s *= __uint_as_float((unsigned)(254 - e) << 23);
  return off + (float)(e - 127) * LN2F;
}

__global__ __launch_bounds__(64, 1) void crf_apply(
    const float* __restrict__ trans, const int* __restrict__ lens,
    const float* __restrict__ pmats, const float* __restrict__ poffs,
    const float* __restrict__ gold_part, float* __restrict__ out) {
  const int lane = threadIdx.x;
  const int b = blockIdx.x;
  const int n = lane & 31;
  const int hb = (lane >> 5) * 16;
  const int len = lens[b];
  const int nc = (len + CH - 1) / CH;
  float s = (n == START) ? 1.0f : 0.0f;
  float off = 0.0f;
  for (int c = 0; c < nc; ++c) {
    const float* pm = pmats + (size_t)(b * NC + c) * (Kn * Kn) + n * Kn + hb;
    const float4 p0 = *(const float4*)pm;
    const float4 p1 = *(const float4*)(pm + 4);
    const float4 p2 = *(const float4*)(pm + 8);
    const float4 p3 = *(const float4*)(pm + 12);
    float a0 = 0.f, a1 = 0.f, a2 = 0.f, a3 = 0.f;
    a0 = fmaf(bcast32(s, hb + 0), p0.x, a0);
    a0 = fmaf(bcast32(s, hb + 1), p0.y, a0);
    a0 = fmaf(bcast32(s, hb + 2), p0.z, a0);
    a0 = fmaf(bcast32(s, hb + 3), p0.w, a0);
    a1 = fmaf(bcast32(s, hb + 4), p1.x, a1);
    a1 = fmaf(bcast32(s, hb + 5), p1.y, a1);
    a1 = fmaf(bcast32(s, hb + 6), p1.z, a1);
    a1 = fmaf(bcast32(s, hb + 7), p1.w, a1);
    a2 = fmaf(bcast32(s, hb + 8), p2.x, a2);
    a2 = fmaf(bcast32(s, hb + 9), p2.y, a2);
    a2 = fmaf(bcast32(s, hb + 10), p2.z, a2);
    a2 = fmaf(bcast32(s, hb + 11), p2.w, a2);
    a3 = fmaf(bcast32(s, hb + 12), p3.x, a3);
    a3 = fmaf(bcast32(s, hb + 13), p3.y, a3);
    a3 = fmaf(bcast32(s, hb + 14), p3.z, a3);
    a3 = fmaf(bcast32(s, hb + 15), p3.w, a3);
    float p = (a0 + a1) + (a2 + a3);
    p += __shfl_xor(p, 32);
    s = p;
    off = renorm_s(s, off);
    off += poffs[b * NC + c];
  }
  const float es = __expf(trans[STOP * Kn + n]);
  float q = s * es;
#pragma unroll
  for (int d = 1; d < 32; d <<= 1) q += __shfl_xor(q, d);
  if (lane == 0) {
    const float fs = __logf(q) + off;
    float gs = 0.f;
#pragma unroll
    for (int p = 0; p < GP; ++p) gs += gold_part[b * GP + p];
    atomicAdd(out, (fs - gs) * (1.0f / (float)Bn));
  }
}

extern "C" void kernel_launch(void* const* d_in, const int* in_sizes, int n_in,
                              void* d_out, int out_size, void* d_ws, size_t ws_size,
                              hipStream_t stream) {
  const float* feats = (const float*)d_in[0];
  const float* trans = (const float*)d_in[1];
  const int* tags = (const int*)d_in[2];
  const int* lens = (const int*)d_in[3];

  // ws layout (floats): [Bn*GP gold][Bn*NC poffs][Bn*NC*1024 pmats]
  float* gold_part = (float*)d_ws;                 // 2048 floats
  float* poffs = gold_part + (size_t)Bn * GP;      // 8192 floats
  float* pmats = poffs + (size_t)Bn * NC;          // 16B-aligned (40960 B)

  hipMemsetAsync(d_out, 0, (size_t)out_size * sizeof(float), stream);
  crf_fused<<<MMB + GB, 256, 0, stream>>>(feats, trans, tags, lens, pmats,
                                          poffs, gold_part);
  crf_apply<<<Bn, 64, 0, stream>>>(trans, lens, pmats, poffs, gold_part,
                                   (float*)d_out);
}